// Round 8
// baseline (140.978 us; speedup 1.0000x reference)
//
#include <hip/hip_runtime.h>
#include <hip/hip_bf16.h>

typedef __bf16 bf16;
typedef bf16 bf16x8 __attribute__((ext_vector_type(8)));
typedef float f32x4 __attribute__((ext_vector_type(4)));

// D = A(16x32) * B(32x16) + C.
// A/B frag: row/col = lane&15, k = (lane>>4)*8 + j (8 contiguous)
// C/D: col = lane&15, row = (lane>>4)*4 + reg   [guide §3, m89-verified]
static __device__ __forceinline__ f32x4 mfma16(bf16x8 a, bf16x8 b, f32x4 c) {
    return __builtin_amdgcn_mfma_f32_16x16x32_bf16(a, b, c, 0, 0, 0);
}

// ---------------------------------------------------------------------------
// Kernel 1: convert weights + rel_emb to bf16. Coalesced READS.
// WF: lane-major fragment layout for proj (12 tiles x 8192).
// Eb: [2304][64], rows >= 2048 zero-padded.
// ---------------------------------------------------------------------------
__global__ __launch_bounds__(256) void cvt_kernel(
    const float* __restrict__ Wq, const float* __restrict__ Wk,
    const float* __restrict__ Wv, const float* __restrict__ rel,
    bf16* __restrict__ WF, bf16* __restrict__ Eb) {
  int i = blockIdx.x * 256 + threadIdx.x;
  if (i < 98304) {                       // W section: 3 * 512 * 64
    int w = i >> 15, rem = i & 32767;
    int k = rem >> 6, n64 = rem & 63;
    const float* W = (w == 0) ? Wq : (w == 1 ? Wk : Wv);
    float v = W[k * 64 + n64];
    int t = w * 4 + (n64 >> 4), rowA = n64 & 15;
    int kcg = k >> 5, kg = (k >> 3) & 3, j = k & 7;
    WF[(((t * 16 + kcg) * 4 + kg) * 16 + rowA) * 8 + j] = (bf16)v;
  } else {
    int j = i - 98304;                   // Eb section: 2304 * 64
    if (j < 147456) Eb[j] = (j < 131072) ? (bf16)rel[j] : (bf16)0.0f;
  }
}

// ---------------------------------------------------------------------------
// Kernel 2: QKV projection. Grid 3072 = (row-block rb, n-group g); 256 thr =
// 4 waves; wave = ONE n-tile (t = g*4+wid). ILP-2 on K (two accumulators).
// 12288 uniform waves, 8 blocks/CU. Q pre-scaled 0.125.
// ---------------------------------------------------------------------------
__global__ __launch_bounds__(256, 8) void proj_kernel(
    const float* __restrict__ x, const bf16* __restrict__ WF,
    const float* __restrict__ bq, const float* __restrict__ bk,
    const float* __restrict__ bv,
    bf16* __restrict__ Qb, bf16* __restrict__ Kb, bf16* __restrict__ Vt) {
  const int wid = threadIdx.x >> 6, lane = threadIdx.x & 63;
  const int rowA = lane & 15, kg = lane >> 4;
  const int g = blockIdx.x % 3;
  const int rb = blockIdx.x / 3;
  const int t = g * 4 + wid;          // n-tile 0..11
  const int r0 = rb * 16;

  f32x4 acc0 = (f32x4){0.f, 0.f, 0.f, 0.f}, acc1 = acc0;
  const float* xp = &x[(size_t)(r0 + rowA) * 512 + kg * 8];
  const bf16* wp = &WF[(size_t)t * 8192 + kg * 128 + rowA * 8];
#pragma unroll
  for (int k2 = 0; k2 < 8; ++k2) {
    float4 x00 = *(const float4*)(xp + k2 * 64);
    float4 x01 = *(const float4*)(xp + k2 * 64 + 4);
    float4 x10 = *(const float4*)(xp + k2 * 64 + 32);
    float4 x11 = *(const float4*)(xp + k2 * 64 + 36);
    bf16x8 af0 = {(bf16)x00.x, (bf16)x00.y, (bf16)x00.z, (bf16)x00.w,
                  (bf16)x01.x, (bf16)x01.y, (bf16)x01.z, (bf16)x01.w};
    bf16x8 af1 = {(bf16)x10.x, (bf16)x10.y, (bf16)x10.z, (bf16)x10.w,
                  (bf16)x11.x, (bf16)x11.y, (bf16)x11.z, (bf16)x11.w};
    bf16x8 wf0 = *(const bf16x8*)(wp + (k2 * 2) * 512);
    bf16x8 wf1 = *(const bf16x8*)(wp + (k2 * 2 + 1) * 512);
    acc0 = mfma16(af0, wf0, acc0);
    acc1 = mfma16(af1, wf1, acc1);
  }
  f32x4 acc = acc0 + acc1;

  int n = t * 16 + rowA;  // C col = lane&15
  float bias = (n < 64) ? bq[n] : (n < 128 ? bk[n - 64] : bv[n - 128]);
#pragma unroll
  for (int j = 0; j < 4; ++j) {
    int R = r0 + kg * 4 + j;  // C row = (lane>>4)*4 + reg
    float v = acc[j] + bias;
    if (n < 64) {
      Qb[(size_t)R * 64 + n] = (bf16)(v * 0.125f);  // fold 1/sqrt(64)
    } else if (n < 128) {
      Kb[(size_t)R * 64 + (n - 64)] = (bf16)v;
    } else {
      int b = R >> 11, tt = R & 2047;
      Vt[((size_t)b * 64 + (n - 128)) * 2048 + tt] = (bf16)v;
    }
  }
}

// ---------------------------------------------------------------------------
// Kernel 3: attention, SINGLE score pass, chunk-PAIR ILP. 512 thr = 8 waves,
// one 16-row q-tile per block, 8-way column split (32-col chunks); each wave
// iterates its chunks TWO at a time (independent branch-free bodies ->
// compiler interleaves, ~2x ILP on the stall-dominated chain).
// Every chunk runs the uniform ntt=2 path: OOB K/E reads land in valid ws
// memory / zero padding and are masked to 0 before use (this also writes the
// diagonal chunk's masked zeros to eCache automatically).
// PV is deferred one pair (unnormalized; scaled by inv at end).
// Phase 2 streams eCache * inv -> outA coalesced (zeros beyond causal).
// Tile mapping (balanced pairs): u=v&31,q=v>>5: i=[2u,127-2u,64+2u,63-2u][q].
// S_rel[r,c] = Q[r] . rel_emb[2047 - r + c]  (c <= r); Q pre-scaled 0.125.
// rel diag via shuffles: el = tt*16+15+rowA-r; src=(kg<<4)|(el&15).
// eCache XOR-swizzle: byte = row*4096 + ((col*2) ^ ((row&7)<<4)).
// ---------------------------------------------------------------------------
__global__ __launch_bounds__(512, 4) void attn_kernel(
    const bf16* __restrict__ Qb, const bf16* __restrict__ Kb,
    const bf16* __restrict__ Vt, const bf16* __restrict__ Eb,
    float* __restrict__ outO, float* __restrict__ outA) {
  __shared__ bf16 eC[16 * 2048];   // 64 KB exp cache (pvRed overlay later)
  __shared__ float sRed[8][16];
  __shared__ float inv16[16];

  const int B = blockIdx.x;
  const int b = B & 7;
  const int v_ = B >> 3;
  const int u = v_ & 31, q = v_ >> 5;
  const int i = (q == 0) ? (u << 1) : (q == 1) ? (127 - (u << 1))
              : (q == 2) ? (64 + (u << 1)) : (63 - (u << 1));
  const int r0 = i << 4;
  const int nCh = (i >> 1) + 1;
  const size_t Rbase = (size_t)b * 2048 + r0;
  const int wid = threadIdx.x >> 6, lane = threadIdx.x & 63;
  const int rowA = lane & 15, kg = lane >> 4;
  char* eCb = (char*)eC;

  bf16x8 qf0 = *(const bf16x8*)&Qb[(Rbase + rowA) * 64 + kg * 8];
  bf16x8 qf1 = *(const bf16x8*)&Qb[(Rbase + rowA) * 64 + 32 + kg * 8];

  int lsrc[4], hi[4];
#pragma unroll
  for (int j = 0; j < 4; ++j) {
    int rl = kg * 4 + j;
    lsrc[j] = (kg << 4) | ((15 + rowA - rl) & 15);
    hi[j] = (rowA > rl);
  }

  float s[4] = {0.f, 0.f, 0.f, 0.f};
  f32x4 pv[4];
#pragma unroll
  for (int ht = 0; ht < 4; ++ht) pv[ht] = (f32x4){0.f, 0.f, 0.f, 0.f};

  // one 32-col chunk, branch-free (uniform ntt=2 with masking)
  auto body = [&](int c0) {
    const int E0 = 2032 + c0 - r0;
    const bf16* ep = &Eb[(size_t)(E0 + rowA) * 64 + kg * 8];
    bf16x8 e00 = *(const bf16x8*)ep;
    bf16x8 e01 = *(const bf16x8*)(ep + 32);
    bf16x8 e10 = *(const bf16x8*)(ep + 1024);
    bf16x8 e11 = *(const bf16x8*)(ep + 1024 + 32);
    bf16x8 e20 = *(const bf16x8*)(ep + 2048);
    bf16x8 e21 = *(const bf16x8*)(ep + 2048 + 32);
    f32x4 a0 = (f32x4){0.f, 0.f, 0.f, 0.f}, a1 = a0, a2 = a0;
    a0 = mfma16(qf0, e00, a0);
    a1 = mfma16(qf0, e10, a1);
    a2 = mfma16(qf0, e20, a2);
    f32x4 R0 = mfma16(qf1, e01, a0);
    f32x4 R1 = mfma16(qf1, e11, a1);
    f32x4 R2 = mfma16(qf1, e21, a2);
    const bf16* kp = &Kb[((size_t)b * 2048 + c0 + rowA) * 64 + kg * 8];
    bf16x8 k00 = *(const bf16x8*)kp;
    bf16x8 k01 = *(const bf16x8*)(kp + 32);
    bf16x8 k10 = *(const bf16x8*)(kp + 1024);
    bf16x8 k11 = *(const bf16x8*)(kp + 1024 + 32);
    f32x4 s0 = (f32x4){0.f, 0.f, 0.f, 0.f}, s1 = s0;
    s0 = mfma16(qf0, k00, s0);
    s1 = mfma16(qf0, k10, s1);
    s0 = mfma16(qf1, k01, s0);
    s1 = mfma16(qf1, k11, s1);
    {  // tt0
      const int c = c0 + rowA;
#pragma unroll
      for (int j = 0; j < 4; ++j) {
        int rl = kg * 4 + j;
        float rlo = __shfl(R0[j], lsrc[j]);
        float rhi = __shfl(R1[j], lsrc[j]);
        float v = s0[j] + (hi[j] ? rhi : rlo);
        float al = (c <= r0 + rl) ? __expf(v) : 0.f;
        s[j] += al;
        *(bf16*)(eCb + rl * 4096 + ((c * 2) ^ ((rl & 7) << 4))) = (bf16)al;
      }
    }
    {  // tt1 (masked lanes write the zeros beyond the diagonal)
      const int c = c0 + 16 + rowA;
#pragma unroll
      for (int j = 0; j < 4; ++j) {
        int rl = kg * 4 + j;
        float rlo = __shfl(R1[j], lsrc[j]);
        float rhi = __shfl(R2[j], lsrc[j]);
        float v = s1[j] + (hi[j] ? rhi : rlo);
        float al = (c <= r0 + rl) ? __expf(v) : 0.f;
        s[j] += al;
        *(bf16*)(eCb + rl * 4096 + ((c * 2) ^ ((rl & 7) << 4))) = (bf16)al;
      }
    }
  };

  auto fire = [&](int pend) {  // deferred PV for one chunk (unnormalized)
    if (pend < 0) return;
    bf16x8 paf = *(const bf16x8*)(eCb + rowA * 4096 +
                                  (((pend + kg * 8) * 2) ^ ((rowA & 7) << 4)));
    const bf16* vp = &Vt[((size_t)b * 64 + rowA) * 2048 + pend + kg * 8];
    pv[0] = mfma16(paf, *(const bf16x8*)vp, pv[0]);
    pv[1] = mfma16(paf, *(const bf16x8*)(vp + 16 * 2048), pv[1]);
    pv[2] = mfma16(paf, *(const bf16x8*)(vp + 32 * 2048), pv[2]);
    pv[3] = mfma16(paf, *(const bf16x8*)(vp + 48 * 2048), pv[3]);
  };

  // ---- main loop: chunk pairs (wave's chunks: wid + 8t) ----
  const int cnt = (wid < nCh) ? ((nCh - wid + 7) >> 3) : 0;
  int c0 = wid << 5;
  int pendA = -1, pendB = -1;
  int t = 0;
  for (; t + 2 <= cnt; t += 2, c0 += 512) {
    fire(pendA);
    fire(pendB);
    body(c0);
    body(c0 + 256);
    pendA = c0;
    pendB = c0 + 256;
  }
  if (t < cnt) {  // odd leftover chunk
    fire(pendA);
    fire(pendB);
    body(c0);
    pendA = c0;
    pendB = -1;
  }
  fire(pendA);
  fire(pendB);

  // ---- denominators: 16-lane shfl reduce, cross-wave via sRed ----
#pragma unroll
  for (int d = 1; d < 16; d <<= 1)
#pragma unroll
    for (int j = 0; j < 4; ++j) s[j] += __shfl_xor(s[j], d);
  if (rowA == 0) {
#pragma unroll
    for (int j = 0; j < 4; ++j) sRed[wid][kg * 4 + j] = s[j];
  }
  __syncthreads();
  if (threadIdx.x < 16) {
    float tt = 0.f;
#pragma unroll
    for (int w = 0; w < 8; ++w) tt += sRed[w][threadIdx.x];
    inv16[threadIdx.x] = 1.f / tt;
  }
  __syncthreads();

  // ---- scale pv by inv (C row = kg*4+j) ----
#pragma unroll
  for (int j = 0; j < 4; ++j) {
    float invj = inv16[kg * 4 + j];
#pragma unroll
    for (int ht = 0; ht < 4; ++ht) pv[ht][j] *= invj;
  }

  // ---- phase 2: stream alpha = eCache * inv -> outA (coalesced float4) ----
  {
    const int row = threadIdx.x >> 5, ln = threadIdx.x & 31;
    const float rinv = inv16[row];
    const int valid = nCh << 5;
    float* orow = &outA[(Rbase + row) * 2048];
#pragma unroll 2
    for (int k = 0; k < 8; ++k) {
      int c = ln * 8 + k * 256;
      float4 o0, o1;
      if (c < valid) {
        bf16x8 e = *(const bf16x8*)(eCb + row * 4096 + ((c * 2) ^ ((row & 7) << 4)));
        o0 = (float4){(float)e[0] * rinv, (float)e[1] * rinv,
                      (float)e[2] * rinv, (float)e[3] * rinv};
        o1 = (float4){(float)e[4] * rinv, (float)e[5] * rinv,
                      (float)e[6] * rinv, (float)e[7] * rinv};
      } else {
        o0 = (float4){0.f, 0.f, 0.f, 0.f};
        o1 = o0;
      }
      *(float4*)(orow + c) = o0;
      *(float4*)(orow + c + 4) = o1;
    }
  }
  __syncthreads();  // eCache dead; overlay pvRed

  // ---- cross-wave PV reduce (pvRed overlays eCache: 32 KB) ----
  float* pvr = (float*)eC;
#pragma unroll
  for (int ht = 0; ht < 4; ++ht)
#pragma unroll
    for (int j = 0; j < 4; ++j)
      pvr[wid * 1024 + ht * 256 + j * 64 + lane] = pv[ht][j];
  __syncthreads();
  for (int o = threadIdx.x; o < 1024; o += 512) {
    float sum = 0.f;
#pragma unroll
    for (int w = 0; w < 8; ++w) sum += pvr[w * 1024 + o];
    int ht = o >> 8, jj = (o >> 6) & 3, l2 = o & 63;
    outO[(Rbase + (l2 >> 4) * 4 + jj) * 64 + ht * 16 + (l2 & 15)] = sum;
  }
}

// ---------------------------------------------------------------------------
extern "C" void kernel_launch(void* const* d_in, const int* in_sizes, int n_in,
                              void* d_out, int out_size, void* d_ws, size_t ws_size,
                              hipStream_t stream) {
  const float* x   = (const float*)d_in[0];
  // d_in[1] = attn_mask: causal tril by construction -> c <= r used directly
  const float* Wq  = (const float*)d_in[2];
  const float* bq  = (const float*)d_in[3];
  const float* Wk  = (const float*)d_in[4];
  const float* bk  = (const float*)d_in[5];
  const float* Wv  = (const float*)d_in[6];
  const float* bv  = (const float*)d_in[7];
  const float* rel = (const float*)d_in[8];

  char* ws = (char*)d_ws;
  bf16* Qb = (bf16*)(ws);                     // 2 MB (pre-scaled 0.125)
  bf16* Kb = (bf16*)(ws + (2u << 20));        // 2 MB
  bf16* Vt = (bf16*)(ws + (4u << 20));        // 2 MB, [b][64][2048]
  bf16* Eb = (bf16*)(ws + (6u << 20));        // 288 KB (zero-padded to 2304)
  bf16* WF = (bf16*)(ws + (6u << 20) + 2304 * 64 * 2);  // 192 KB frag layout

  float* outO = (float*)d_out;                       // [8,2048,64]
  float* outA = outO + (size_t)8 * 2048 * 64;        // [8,2048,2048]

  cvt_kernel<<<960, 256, 0, stream>>>(Wq, Wk, Wv, rel, WF, Eb);
  proj_kernel<<<3072, 256, 0, stream>>>(x, WF, bq, bk, bv, Qb, Kb, Vt);
  attn_kernel<<<1024, 512, 0, stream>>>(Qb, Kb, Vt, Eb, outO, outA);
}

// Round 10
// 116.530 us; speedup vs baseline: 1.2098x; 1.2098x over previous
//
#include <hip/hip_runtime.h>
#include <hip/hip_bf16.h>

typedef __bf16 bf16;
typedef bf16 bf16x8 __attribute__((ext_vector_type(8)));
typedef float f32x4 __attribute__((ext_vector_type(4)));

// D = A(16x32) * B(32x16) + C.
// A/B frag: row/col = lane&15, k = (lane>>4)*8 + j (8 contiguous)
// C/D: col = lane&15, row = (lane>>4)*4 + reg   [guide §3, m89-verified]
static __device__ __forceinline__ f32x4 mfma16(bf16x8 a, bf16x8 b, f32x4 c) {
    return __builtin_amdgcn_mfma_f32_16x16x32_bf16(a, b, c, 0, 0, 0);
}

// ---------------------------------------------------------------------------
// Kernel 1: convert weights + rel_emb to bf16. Coalesced READS.
// WF: lane-major fragment layout for proj (12 tiles x 8192).
// Eb: [2304][64], rows >= 2048 zero-padded.
// ---------------------------------------------------------------------------
__global__ __launch_bounds__(256) void cvt_kernel(
    const float* __restrict__ Wq, const float* __restrict__ Wk,
    const float* __restrict__ Wv, const float* __restrict__ rel,
    bf16* __restrict__ WF, bf16* __restrict__ Eb) {
  int i = blockIdx.x * 256 + threadIdx.x;
  if (i < 98304) {                       // W section: 3 * 512 * 64
    int w = i >> 15, rem = i & 32767;
    int k = rem >> 6, n64 = rem & 63;
    const float* W = (w == 0) ? Wq : (w == 1 ? Wk : Wv);
    float v = W[k * 64 + n64];
    int t = w * 4 + (n64 >> 4), rowA = n64 & 15;
    int kcg = k >> 5, kg = (k >> 3) & 3, j = k & 7;
    WF[(((t * 16 + kcg) * 4 + kg) * 16 + rowA) * 8 + j] = (bf16)v;
  } else {
    int j = i - 98304;                   // Eb section: 2304 * 64
    if (j < 147456) Eb[j] = (j < 131072) ? (bf16)rel[j] : (bf16)0.0f;
  }
}

// ---------------------------------------------------------------------------
// Kernel 2: QKV projection (R7-proven). 256 thr = 4 waves sharing 16 x-rows;
// wave owns 3 n-tiles. W loads fully coalesced via WF. Q pre-scaled 0.125.
// ---------------------------------------------------------------------------
__global__ __launch_bounds__(256, 4) void proj_kernel(
    const float* __restrict__ x, const bf16* __restrict__ WF,
    const float* __restrict__ bq, const float* __restrict__ bk,
    const float* __restrict__ bv,
    bf16* __restrict__ Qb, bf16* __restrict__ Kb, bf16* __restrict__ Vt) {
  const int wid = threadIdx.x >> 6, lane = threadIdx.x & 63;
  const int rowA = lane & 15, kg = lane >> 4;
  const int r0 = blockIdx.x * 16;
  const int t0 = wid * 3;

  f32x4 acc[3];
#pragma unroll
  for (int tt = 0; tt < 3; ++tt) acc[tt] = (f32x4){0.f, 0.f, 0.f, 0.f};

  const float* xp = &x[(size_t)(r0 + rowA) * 512 + kg * 8];
  const bf16* wp = &WF[(size_t)t0 * 8192 + kg * 128 + rowA * 8];
#pragma unroll 4
  for (int kcg = 0; kcg < 16; ++kcg) {
    float4 xv0 = *(const float4*)(xp + kcg * 32);
    float4 xv1 = *(const float4*)(xp + kcg * 32 + 4);
    bf16x8 af = {(bf16)xv0.x, (bf16)xv0.y, (bf16)xv0.z, (bf16)xv0.w,
                 (bf16)xv1.x, (bf16)xv1.y, (bf16)xv1.z, (bf16)xv1.w};
#pragma unroll
    for (int tt = 0; tt < 3; ++tt) {
      bf16x8 wf = *(const bf16x8*)(wp + tt * 8192 + kcg * 512);
      acc[tt] = mfma16(af, wf, acc[tt]);
    }
  }
#pragma unroll
  for (int tt = 0; tt < 3; ++tt) {
    int n = (t0 + tt) * 16 + rowA;  // C col = lane&15
    float bias = (n < 64) ? bq[n] : (n < 128 ? bk[n - 64] : bv[n - 128]);
#pragma unroll
    for (int j = 0; j < 4; ++j) {
      int R = r0 + kg * 4 + j;  // C row = (lane>>4)*4 + reg
      float v = acc[tt][j] + bias;
      if (n < 64) {
        Qb[(size_t)R * 64 + n] = (bf16)(v * 0.125f);  // fold 1/sqrt(64)
      } else if (n < 128) {
        Kb[(size_t)R * 64 + (n - 64)] = (bf16)v;
      } else {
        int b = R >> 11, t = R & 2047;
        Vt[((size_t)b * 64 + (n - 128)) * 2048 + t] = (bf16)v;
      }
    }
  }
}

// ---------------------------------------------------------------------------
// Kernel 3: attention, single score pass, PERSISTENT balanced blocks.
// Grid 512 = (b, u): block processes tile pair {u, 127-u} sequentially --
// identical total work per block (67 chunks), exactly 2 blocks/CU resident
// for the whole kernel (no drain). Per tile (16 q-rows, 8 waves, 8-way
// 32-col chunk split):
//   phase 1: QK+rel (uniform branch-free ntt=2 w/ masking) -> exp ->
//     bf16 eCache (64KB LDS, XOR swizzle (c*2)^((row&7)<<4)) + denom acc +
//     one-chunk-deferred PV on unnormalized values.
//   denom reduce -> inv; pv *= inv.
//   phase 2: stream eCache * inv -> outA via NONTEMPORAL f32x4 (zeros
//     beyond causal region); then pvRed overlay -> outO.
// S_rel[r,c] = Q[r] . rel_emb[2047 - r + c]  (c <= r); Q pre-scaled 0.125.
// rel diag via shuffles: el = tt*16+15+rowA-r; src=(kg<<4)|(el&15).
// ---------------------------------------------------------------------------
__global__ __launch_bounds__(512, 4) void attn_kernel(
    const bf16* __restrict__ Qb, const bf16* __restrict__ Kb,
    const bf16* __restrict__ Vt, const bf16* __restrict__ Eb,
    float* __restrict__ outO, float* __restrict__ outA) {
  __shared__ bf16 eC[16 * 2048];   // 64 KB exp cache (pvRed overlay later)
  __shared__ float sRed[8][16];
  __shared__ float inv16[16];

  const int B = blockIdx.x;
  const int b = B & 7;
  const int u = B >> 3;            // 0..63
  const int wid = threadIdx.x >> 6, lane = threadIdx.x & 63;
  const int rowA = lane & 15, kg = lane >> 4;
  char* eCb = (char*)eC;

  int lsrc[4], hi[4];
#pragma unroll
  for (int j = 0; j < 4; ++j) {
    int rl = kg * 4 + j;
    lsrc[j] = (kg << 4) | ((15 + rowA - rl) & 15);
    hi[j] = (rowA > rl);
  }

  for (int half = 0; half < 2; ++half) {
    const int i = half ? (127 - u) : u;
    const int r0 = i << 4;
    const int nCh = (i >> 1) + 1;
    const size_t Rbase = (size_t)b * 2048 + r0;

    bf16x8 qf0 = *(const bf16x8*)&Qb[(Rbase + rowA) * 64 + kg * 8];
    bf16x8 qf1 = *(const bf16x8*)&Qb[(Rbase + rowA) * 64 + 32 + kg * 8];

    float s[4] = {0.f, 0.f, 0.f, 0.f};
    f32x4 pv[4];
#pragma unroll
    for (int ht = 0; ht < 4; ++ht) pv[ht] = (f32x4){0.f, 0.f, 0.f, 0.f};

    // ---- phase 1: chunks wid, wid+8, ...; one-chunk-deferred PV ----
    int pend = -1;
    for (int ch = wid; ch < nCh; ch += 8) {
      const int c0 = ch << 5;
      // stage deferred PV inputs (precede this chunk's eC writes)
      bf16x8 paf, pvf0, pvf1, pvf2, pvf3;
      if (pend >= 0) {
        paf = *(const bf16x8*)(eCb + rowA * 4096 +
                               (((pend + kg * 8) * 2) ^ ((rowA & 7) << 4)));
        const bf16* vp = &Vt[((size_t)b * 64 + rowA) * 2048 + pend + kg * 8];
        pvf0 = *(const bf16x8*)vp;
        pvf1 = *(const bf16x8*)(vp + 16 * 2048);
        pvf2 = *(const bf16x8*)(vp + 32 * 2048);
        pvf3 = *(const bf16x8*)(vp + 48 * 2048);
      }
      // uniform branch-free chunk body (ntt=2 path w/ masking; Eb padded)
      const int E0 = 2032 + c0 - r0;
      const bf16* ep = &Eb[(size_t)(E0 + rowA) * 64 + kg * 8];
      bf16x8 e00 = *(const bf16x8*)ep;
      bf16x8 e01 = *(const bf16x8*)(ep + 32);
      bf16x8 e10 = *(const bf16x8*)(ep + 1024);
      bf16x8 e11 = *(const bf16x8*)(ep + 1024 + 32);
      bf16x8 e20 = *(const bf16x8*)(ep + 2048);
      bf16x8 e21 = *(const bf16x8*)(ep + 2048 + 32);
      f32x4 a0 = (f32x4){0.f, 0.f, 0.f, 0.f}, a1 = a0, a2 = a0;
      a0 = mfma16(qf0, e00, a0);
      a1 = mfma16(qf0, e10, a1);
      a2 = mfma16(qf0, e20, a2);
      f32x4 R0 = mfma16(qf1, e01, a0);
      f32x4 R1 = mfma16(qf1, e11, a1);
      f32x4 R2 = mfma16(qf1, e21, a2);
      const bf16* kp = &Kb[((size_t)b * 2048 + c0 + rowA) * 64 + kg * 8];
      bf16x8 k00 = *(const bf16x8*)kp;
      bf16x8 k01 = *(const bf16x8*)(kp + 32);
      bf16x8 k10 = *(const bf16x8*)(kp + 1024);
      bf16x8 k11 = *(const bf16x8*)(kp + 1024 + 32);
      f32x4 s0 = (f32x4){0.f, 0.f, 0.f, 0.f}, s1 = s0;
      s0 = mfma16(qf0, k00, s0);
      s1 = mfma16(qf0, k10, s1);
      s0 = mfma16(qf1, k01, s0);
      s1 = mfma16(qf1, k11, s1);
      {  // tt0
        const int c = c0 + rowA;
#pragma unroll
        for (int j = 0; j < 4; ++j) {
          int rl = kg * 4 + j;
          float rlo = __shfl(R0[j], lsrc[j]);
          float rhi = __shfl(R1[j], lsrc[j]);
          float v = s0[j] + (hi[j] ? rhi : rlo);
          float al = (c <= r0 + rl) ? __expf(v) : 0.f;
          s[j] += al;
          *(bf16*)(eCb + rl * 4096 + ((c * 2) ^ ((rl & 7) << 4))) = (bf16)al;
        }
      }
      {  // tt1 (masked lanes write the beyond-diagonal zeros)
        const int c = c0 + 16 + rowA;
#pragma unroll
        for (int j = 0; j < 4; ++j) {
          int rl = kg * 4 + j;
          float rlo = __shfl(R1[j], lsrc[j]);
          float rhi = __shfl(R2[j], lsrc[j]);
          float v = s1[j] + (hi[j] ? rhi : rlo);
          float al = (c <= r0 + rl) ? __expf(v) : 0.f;
          s[j] += al;
          *(bf16*)(eCb + rl * 4096 + ((c * 2) ^ ((rl & 7) << 4))) = (bf16)al;
        }
      }
      // fire deferred PV (unnormalized)
      if (pend >= 0) {
        pv[0] = mfma16(paf, pvf0, pv[0]);
        pv[1] = mfma16(paf, pvf1, pv[1]);
        pv[2] = mfma16(paf, pvf2, pv[2]);
        pv[3] = mfma16(paf, pvf3, pv[3]);
      }
      pend = c0;
    }
    if (pend >= 0) {  // drain
      bf16x8 paf = *(const bf16x8*)(eCb + rowA * 4096 +
                                    (((pend + kg * 8) * 2) ^ ((rowA & 7) << 4)));
      const bf16* vp = &Vt[((size_t)b * 64 + rowA) * 2048 + pend + kg * 8];
      pv[0] = mfma16(paf, *(const bf16x8*)vp, pv[0]);
      pv[1] = mfma16(paf, *(const bf16x8*)(vp + 16 * 2048), pv[1]);
      pv[2] = mfma16(paf, *(const bf16x8*)(vp + 32 * 2048), pv[2]);
      pv[3] = mfma16(paf, *(const bf16x8*)(vp + 48 * 2048), pv[3]);
    }

    // ---- denominators ----
#pragma unroll
    for (int d = 1; d < 16; d <<= 1)
#pragma unroll
      for (int j = 0; j < 4; ++j) s[j] += __shfl_xor(s[j], d);
    if (rowA == 0) {
#pragma unroll
      for (int j = 0; j < 4; ++j) sRed[wid][kg * 4 + j] = s[j];
    }
    __syncthreads();
    if (threadIdx.x < 16) {
      float tt = 0.f;
#pragma unroll
      for (int w = 0; w < 8; ++w) tt += sRed[w][threadIdx.x];
      inv16[threadIdx.x] = 1.f / tt;
    }
    __syncthreads();

    // ---- scale pv by inv (C row = kg*4+j) ----
#pragma unroll
    for (int j = 0; j < 4; ++j) {
      float invj = inv16[kg * 4 + j];
#pragma unroll
      for (int ht = 0; ht < 4; ++ht) pv[ht][j] *= invj;
    }

    // ---- phase 2: stream alpha = eCache * inv -> outA (NT f32x4) ----
    {
      const int row = threadIdx.x >> 5, ln = threadIdx.x & 31;
      const float rinv = inv16[row];
      const int valid = nCh << 5;
      float* orow = &outA[(Rbase + row) * 2048];
#pragma unroll 2
      for (int k = 0; k < 8; ++k) {
        int c = ln * 8 + k * 256;
        f32x4 o0, o1;
        if (c < valid) {
          bf16x8 e = *(const bf16x8*)(eCb + row * 4096 +
                                      ((c * 2) ^ ((row & 7) << 4)));
          o0 = (f32x4){(float)e[0] * rinv, (float)e[1] * rinv,
                       (float)e[2] * rinv, (float)e[3] * rinv};
          o1 = (f32x4){(float)e[4] * rinv, (float)e[5] * rinv,
                       (float)e[6] * rinv, (float)e[7] * rinv};
        } else {
          o0 = (f32x4){0.f, 0.f, 0.f, 0.f};
          o1 = o0;
        }
        __builtin_nontemporal_store(o0, (f32x4*)(orow + c));
        __builtin_nontemporal_store(o1, (f32x4*)(orow + c + 4));
      }
    }
    __syncthreads();  // eCache dead; overlay pvRed

    // ---- cross-wave PV reduce (pvRed overlays eCache: 32 KB) ----
    float* pvr = (float*)eC;
#pragma unroll
    for (int ht = 0; ht < 4; ++ht)
#pragma unroll
      for (int j = 0; j < 4; ++j)
        pvr[wid * 1024 + ht * 256 + j * 64 + lane] = pv[ht][j];
    __syncthreads();
    for (int o = threadIdx.x; o < 1024; o += 512) {
      float sum = 0.f;
#pragma unroll
      for (int w = 0; w < 8; ++w) sum += pvr[w * 1024 + o];
      int ht = o >> 8, jj = (o >> 6) & 3, l2 = o & 63;
      outO[(Rbase + (l2 >> 4) * 4 + jj) * 64 + ht * 16 + (l2 & 15)] = sum;
    }
    __syncthreads();  // protect eC before next tile's phase 1
  }
}

// ---------------------------------------------------------------------------
extern "C" void kernel_launch(void* const* d_in, const int* in_sizes, int n_in,
                              void* d_out, int out_size, void* d_ws, size_t ws_size,
                              hipStream_t stream) {
  const float* x   = (const float*)d_in[0];
  // d_in[1] = attn_mask: causal tril by construction -> c <= r used directly
  const float* Wq  = (const float*)d_in[2];
  const float* bq  = (const float*)d_in[3];
  const float* Wk  = (const float*)d_in[4];
  const float* bk  = (const float*)d_in[5];
  const float* Wv  = (const float*)d_in[6];
  const float* bv  = (const float*)d_in[7];
  const float* rel = (const float*)d_in[8];

  char* ws = (char*)d_ws;
  bf16* Qb = (bf16*)(ws);                     // 2 MB (pre-scaled 0.125)
  bf16* Kb = (bf16*)(ws + (2u << 20));        // 2 MB
  bf16* Vt = (bf16*)(ws + (4u << 20));        // 2 MB, [b][64][2048]
  bf16* Eb = (bf16*)(ws + (6u << 20));        // 288 KB (zero-padded to 2304)
  bf16* WF = (bf16*)(ws + (6u << 20) + 2304 * 64 * 2);  // 192 KB frag layout

  float* outO = (float*)d_out;                       // [8,2048,64]
  float* outA = outO + (size_t)8 * 2048 * 64;        // [8,2048,2048]

  cvt_kernel<<<960, 256, 0, stream>>>(Wq, Wk, Wv, rel, WF, Eb);
  proj_kernel<<<1024, 256, 0, stream>>>(x, WF, bq, bk, bv, Qb, Kb, Vt);
  attn_kernel<<<512, 512, 0, stream>>>(Qb, Kb, Vt, Eb, outO, outA);
}